// Round 16
// baseline (902.178 us; speedup 1.0000x reference)
//
#include <hip/hip_runtime.h>
#include <hip/hip_bf16.h>
#include <stdint.h>

// GRU sequence decoder, fused. B=32768, H=L=512, VOCAB=10, SEQ=6.
// R16 = R10 (573us best: h dbuf in LDS, one barrier/step, gi in ws with
// pass-head prefetch, wn8 partition, unroll 4) with ONE change: the LDS
// layout is R11's k-major padded scheme instead of the XOR swizzle.
//   h stored as 64 chunks (8 bf16 of k x 64 rows, 16B/row), chunk stride
//   CH=1040B (16B pad). ds_read addr = base + kk*4160 + bt*256 -> pure
//   compile-time immediates: no v_xor/v_add per LDS access (R10 paid ~20
//   VALU/kk), loads issue back-to-back. Bank phases = same minimum as R10.
//   (R11 proved this layout correct; its slowdown was the gireg spill,
//   which R16 does NOT carry — gi stays in ws, gpre[3][4]=24 regs.)
// Register model (R2/R11-R15): acc 48 AGPR + ~128 arch = R10's proven
// no-spill point; BM=128 family abandoned (structurally spills).
// __launch_bounds__(512,1), NBLK=512, 1 block/CU (R7/R8: 2nd never resides).

typedef __bf16 bf16_t;
typedef bf16_t bf16x8 __attribute__((ext_vector_type(8)));
typedef bf16_t bf16x4 __attribute__((ext_vector_type(4)));
typedef float  f32x4  __attribute__((ext_vector_type(4)));
typedef float  f32x2  __attribute__((ext_vector_type(2)));

#define THREADS 512
#define BM      64
#define NBLK    512
#define NSTEP   6
#define CH      1040              // chunk stride bytes (1024 + 16 pad)
#define BUFB    (64 * CH)         // one h buffer: 66560 B

// ws layout (bytes)
#define WIH_OFF 0u            // 96 nt * 16 kk * 64 lane * 16B = 1572864
#define WHH_OFF 1572864u
#define WOP_OFF 3145728u      // 16 kk * 64 lane * 16B = 16384
#define GI_OFF  4194304u      // 512 blk * 24576 chunks * 8B = 100663296

static __device__ __forceinline__ float sigm(float v) { return 1.0f / (1.0f + __expf(-v)); }
static __device__ __forceinline__ float tanhf_(float v) {
  v = fminf(fmaxf(v, -12.0f), 12.0f);
  float e = __expf(2.0f * v);
  return 1.0f - 2.0f / (e + 1.0f);
}
static __device__ __forceinline__ f32x4 up4(bf16x4 v) {
  f32x4 o; o[0] = (float)v[0]; o[1] = (float)v[1]; o[2] = (float)v[2]; o[3] = (float)v[3];
  return o;
}
static __device__ __forceinline__ bf16x4 pk4(f32x4 v) {
  bf16x4 o; o[0] = (bf16_t)v[0]; o[1] = (bf16_t)v[1]; o[2] = (bf16_t)v[2]; o[3] = (bf16_t)v[3];
  return o;
}

// Pack weights into MFMA A-frag order:
//   chunk[(nt*16 + kk)*64 + lane] = w[nt*16 + (lane&15)][kk*32 + (lane>>4)*8 .. +8]
__global__ void prep_kernel(const float* __restrict__ wih_f, const float* __restrict__ whh_f,
                            const float* __restrict__ wout_f,
                            bf16x8* __restrict__ wihPk, bf16x8* __restrict__ whhPk,
                            bf16x8* __restrict__ wopPk) {
  int c = blockIdx.x * 256 + threadIdx.x;
  int lane = c & 63, l15 = lane & 15, lk = (lane >> 4) & 3;
  if (c < 196608) {
    int cid = (c < 98304) ? c : c - 98304;
    const float* src = (c < 98304) ? wih_f : whh_f;
    bf16x8* dst = (c < 98304) ? wihPk : whhPk;
    int kk = (cid >> 6) & 15;
    int nt = cid >> 10;
    const float* p = src + (size_t)(nt * 16 + l15) * 512 + kk * 32 + lk * 8;
    bf16x8 o;
    #pragma unroll
    for (int i = 0; i < 8; ++i) o[i] = (bf16_t)p[i];
    dst[cid] = o;
  } else if (c < 197632) {
    int cid = c - 196608;          // vocab tile: 16 kk * 64 lane
    int kk = cid >> 6;
    bf16x8 o;
    if (l15 < 10) {
      const float* p = wout_f + (size_t)l15 * 512 + kk * 32 + lk * 8;
      #pragma unroll
      for (int i = 0; i < 8; ++i) o[i] = (bf16_t)p[i];
    } else {
      #pragma unroll
      for (int i = 0; i < 8; ++i) o[i] = (bf16_t)0.0f;
    }
    wopPk[cid] = o;
  }
}

__global__ __launch_bounds__(THREADS, 1) void gru_kernel(
    const float* __restrict__ x, const float* __restrict__ b_ih,
    const float* __restrict__ b_hh, const float* __restrict__ b_out,
    const bf16x8* __restrict__ wih, const bf16x8* __restrict__ whh,
    const bf16x8* __restrict__ wop,
    bf16x4* __restrict__ gi, float* __restrict__ out) {
  // Two h buffers, k-major: chunk c holds k in [c*8, c*8+8) x 64 rows
  // (16B/row), chunk stride CH=1040. Step t reads cur, ds_writes nxt,
  // ONE barrier, swap.
  __shared__ __align__(16) char hlds[2 * BUFB];

  const int tid   = (int)threadIdx.x;
  const int lane  = tid & 63;
  const int wq    = tid >> 6;      // 0..7: wave owns jtiles [wq*4, wq*4+4)
  const int l15   = lane & 15;
  const int lk    = lane >> 4;
  const int brow0 = (int)blockIdx.x * BM;

  char* cur = hlds;             // h_t
  char* nxt = hlds + BUFB;      // h_{t+1}

  // ---------------- phase 0: x -> bf16 -> cur (h0 = x), k-major ----------
  #pragma unroll
  for (int it = 0; it < 16; ++it) {
    int f4  = it * THREADS + tid;
    int row = f4 >> 7, c4 = f4 & 127;          // c4 = 4-float group (k = c4*4)
    float4 v = ((const float4*)(x + (size_t)(brow0 + row) * 512))[c4];
    bf16x4 h4 = { (bf16_t)v.x, (bf16_t)v.y, (bf16_t)v.z, (bf16_t)v.w };
    *(bf16x4*)(&cur[(c4 >> 1) * CH + row * 16 + (c4 & 1) * 8]) = h4;
  }
  __syncthreads();

  const size_t gibase = (size_t)blockIdx.x * 24576;  // bf16x4 chunks per block
  // gi chunk: (jt*12 + g*4 + bt)*64 + lane,  jt = wq*4 + p

  // B-frag base: lane group lk reads chunk kk*4+lk, row l15 (+bt*16)
  // cell base: j-slice of jt at chunk jt*2+(lk>>1), byte (lk&1)*8

  // ---------------- gi phase: gi = x @ w_ih^T + biases ----------------
  {
    const char* aB = cur + lk * CH + l15 * 16;   // + kk*4160 + bt*256 (imm)
    #pragma unroll
    for (int p = 0; p < 4; ++p) {
      const int jt = wq * 4 + p;
      f32x4 acc[3][4];
      #pragma unroll
      for (int g = 0; g < 3; ++g)
        #pragma unroll
        for (int bt = 0; bt < 4; ++bt) acc[g][bt] = (f32x4){0.f, 0.f, 0.f, 0.f};

      #pragma unroll 4
      for (int kk = 0; kk < 16; ++kk) {
        bf16x8 hf[4];
        #pragma unroll
        for (int bt = 0; bt < 4; ++bt)
          hf[bt] = *(const bf16x8*)(aB + kk * 4160 + bt * 256);
        #pragma unroll
        for (int g = 0; g < 3; ++g) {
          bf16x8 wf = wih[((g * 32 + jt) * 16 + kk) * 64 + lane];
          #pragma unroll
          for (int bt = 0; bt < 4; ++bt)
            acc[g][bt] = __builtin_amdgcn_mfma_f32_16x16x32_bf16(wf, hf[bt], acc[g][bt], 0, 0, 0);
        }
      }
      {
        int j = jt * 16 + lk * 4;
        f32x4 b0 = *(const f32x4*)(b_ih + j) + *(const f32x4*)(b_hh + j);
        f32x4 b1 = *(const f32x4*)(b_ih + 512 + j) + *(const f32x4*)(b_hh + 512 + j);
        f32x4 b2 = *(const f32x4*)(b_ih + 1024 + j);   // b_hh_n stays separate (x r)
        #pragma unroll
        for (int bt = 0; bt < 4; ++bt) {
          int cb = jt * 12 + bt;
          gi[gibase + ((size_t)(cb + 0) << 6) + lane] = pk4(acc[0][bt] + b0);
          gi[gibase + ((size_t)(cb + 4) << 6) + lane] = pk4(acc[1][bt] + b1);
          gi[gibase + ((size_t)(cb + 8) << 6) + lane] = pk4(acc[2][bt] + b2);
        }
      }
    }
  }
  // (no barrier: cur unchanged; gi is same-lane RAW, HW-ordered)

  // ---------------- 6 recurrent steps (one barrier each) ----------------
  for (int t = 0; t < NSTEP; ++t) {
    const char* aB = cur + lk * CH + l15 * 16;
    #pragma unroll
    for (int p = 0; p < 4; ++p) {
      const int jt = wq * 4 + p;
      const int cb = jt * 12;

      // prefetch this pass's 12 gi chunks (latency hides under the k-loop)
      bf16x4 gpre[3][4];
      #pragma unroll
      for (int g = 0; g < 3; ++g)
        #pragma unroll
        for (int bt = 0; bt < 4; ++bt)
          gpre[g][bt] = gi[gibase + ((size_t)(cb + g * 4 + bt) << 6) + lane];

      f32x4 acc[3][4];
      #pragma unroll
      for (int g = 0; g < 3; ++g)
        #pragma unroll
        for (int bt = 0; bt < 4; ++bt) acc[g][bt] = (f32x4){0.f, 0.f, 0.f, 0.f};

      #pragma unroll 4
      for (int kk = 0; kk < 16; ++kk) {
        bf16x8 hf[4];
        #pragma unroll
        for (int bt = 0; bt < 4; ++bt)
          hf[bt] = *(const bf16x8*)(aB + kk * 4160 + bt * 256);
        #pragma unroll
        for (int g = 0; g < 3; ++g) {
          bf16x8 wf = whh[((g * 32 + jt) * 16 + kk) * 64 + lane];
          #pragma unroll
          for (int bt = 0; bt < 4; ++bt)
            acc[g][bt] = __builtin_amdgcn_mfma_f32_16x16x32_bf16(wf, hf[bt], acc[g][bt], 0, 0, 0);
        }
      }
      // GRU cell epilogue: gi from regs; h_old from LDS (imm addr);
      // h_new ds_written straight into nxt (no reg hold, no global trip).
      {
        int j = jt * 16 + lk * 4;
        f32x4 bn4 = *(const f32x4*)(b_hh + 1024 + j);
        const int cof = (jt * 2 + (lk >> 1)) * CH + l15 * 16 + (lk & 1) * 8;
        #pragma unroll
        for (int bt = 0; bt < 4; ++bt) {
          f32x4 gr  = up4(gpre[0][bt]);
          f32x4 gz  = up4(gpre[1][bt]);
          f32x4 gn  = up4(gpre[2][bt]);
          f32x4 hov = up4(*(const bf16x4*)(cur + cof + bt * 256));
          f32x4 hv;
          #pragma unroll
          for (int r = 0; r < 4; ++r) {
            float rv = sigm(gr[r] + acc[0][bt][r]);
            float zv = sigm(gz[r] + acc[1][bt][r]);
            float nv = tanhf_(gn[r] + rv * (acc[2][bt][r] + bn4[r]));
            hv[r] = zv * (hov[r] - nv) + nv;     // = (1-z)*n + z*h
          }
          *(bf16x4*)(nxt + cof + bt * 256) = pk4(hv);
        }
      }
    }
    __syncthreads();   // h_{t+1} writes drained & visible; h_t reads all done

    { char* tmp = cur; cur = nxt; nxt = tmp; }   // cur = h_{t+1}

    // logits_t = h_{t+1} @ w_out^T + b_out ; waves 0..3 each own one btile.
    // Concurrent with other waves' next-step k-loop (both only read cur;
    // epilogue writes go to nxt — disjoint).
    if (wq < 4) {
      const char* aL = cur + lk * CH + l15 * 16 + wq * 256;
      f32x4 lacc = (f32x4){0.f, 0.f, 0.f, 0.f};
      #pragma unroll 4
      for (int kk = 0; kk < 16; ++kk) {
        bf16x8 hf = *(const bf16x8*)(aL + kk * 4160);
        bf16x8 wf = wop[kk * 64 + lane];
        lacc = __builtin_amdgcn_mfma_f32_16x16x32_bf16(wf, hf, lacc, 0, 0, 0);
      }
      size_t ob = (size_t)(brow0 + wq * 16 + l15) * 60 + t * 10 + lk * 4;
      if (lk < 2) {
        f32x2 a = { lacc[0] + b_out[lk * 4 + 0], lacc[1] + b_out[lk * 4 + 1] };
        f32x2 b = { lacc[2] + b_out[lk * 4 + 2], lacc[3] + b_out[lk * 4 + 3] };
        *(f32x2*)(out + ob) = a;
        *(f32x2*)(out + ob + 2) = b;
      } else if (lk == 2) {
        f32x2 a = { lacc[0] + b_out[8], lacc[1] + b_out[9] };
        *(f32x2*)(out + ob) = a;
      }
    }
  }
}

extern "C" void kernel_launch(void* const* d_in, const int* in_sizes, int n_in,
                              void* d_out, int out_size, void* d_ws, size_t ws_size,
                              hipStream_t stream) {
  const float* x     = (const float*)d_in[0];
  const float* wih_f = (const float*)d_in[1];
  const float* whh_f = (const float*)d_in[2];
  const float* b_ih  = (const float*)d_in[3];
  const float* b_hh  = (const float*)d_in[4];
  const float* wout  = (const float*)d_in[5];
  const float* b_out = (const float*)d_in[6];

  char* ws = (char*)d_ws;
  bf16x8* wihPk = (bf16x8*)(ws + WIH_OFF);
  bf16x8* whhPk = (bf16x8*)(ws + WHH_OFF);
  bf16x8* wopPk = (bf16x8*)(ws + WOP_OFF);
  bf16x4* gi    = (bf16x4*)(ws + GI_OFF);

  prep_kernel<<<772, 256, 0, stream>>>(wih_f, whh_f, wout, wihPk, whhPk, wopPk);
  gru_kernel<<<NBLK, THREADS, 0, stream>>>(x, b_ih, b_hh, b_out,
                                           wihPk, whhPk, wopPk, gi, (float*)d_out);
}

// Round 17
// 690.944 us; speedup vs baseline: 1.3057x; 1.3057x over previous
//
#include <hip/hip_runtime.h>
#include <hip/hip_bf16.h>
#include <stdint.h>

// GRU sequence decoder, fused. B=32768, H=L=512, VOCAB=10, SEQ=6.
// R17 = R10 (573us best) with ONE change: the 6-step loop is unrolled x2
// with COMPILE-TIME h buffer selection (hA/hB instead of runtime-swapped
// cur/nxt). Mechanism: R10's runtime swap made ds_write(nxt) vs ds_read(cur)
// alias-ambiguous -> the scheduler could not slide pass p's epilogue under
// pass p+1's k-loop; with constant bases the sets are provably disjoint and
// the epilogue (VALU pipe + gi loads) overlaps the next pass's MFMA pipe
// (m114: separate pipes co-issue). No register-budget change vs R10.
// R16 lesson: immediate-only LDS addressing removes the XOR chain but lets
// the scheduler hoist too many loads -> spill; keep R10's XOR addressing.
// Structure (R10): 8 waves, wave owns jtiles [wq*4,wq*4+4) x 4 btiles;
// h double-buffered in LDS (XOR swizzle byte^=(row&7)<<4), one barrier/step;
// gi in ws per-lane frag order w/ pass-head prefetch (24 regs); weights
// pre-packed frag order (L2-resident); logits on waves 0-3 post-barrier.
// __launch_bounds__(512,1), NBLK=512, 1 block/CU.

typedef __bf16 bf16_t;
typedef bf16_t bf16x8 __attribute__((ext_vector_type(8)));
typedef bf16_t bf16x4 __attribute__((ext_vector_type(4)));
typedef float  f32x4  __attribute__((ext_vector_type(4)));
typedef float  f32x2  __attribute__((ext_vector_type(2)));

#define THREADS 512
#define BM      64
#define NBLK    512
#define NSTEP   6
#define BUFB    (BM * 1024)

// ws layout (bytes)
#define WIH_OFF 0u            // 96 nt * 16 kk * 64 lane * 16B = 1572864
#define WHH_OFF 1572864u
#define WOP_OFF 3145728u      // 16 kk * 64 lane * 16B = 16384
#define GI_OFF  4194304u      // 512 blk * 24576 chunks * 8B = 100663296

static __device__ __forceinline__ float sigm(float v) { return 1.0f / (1.0f + __expf(-v)); }
static __device__ __forceinline__ float tanhf_(float v) {
  v = fminf(fmaxf(v, -12.0f), 12.0f);
  float e = __expf(2.0f * v);
  return 1.0f - 2.0f / (e + 1.0f);
}
static __device__ __forceinline__ f32x4 up4(bf16x4 v) {
  f32x4 o; o[0] = (float)v[0]; o[1] = (float)v[1]; o[2] = (float)v[2]; o[3] = (float)v[3];
  return o;
}
static __device__ __forceinline__ bf16x4 pk4(f32x4 v) {
  bf16x4 o; o[0] = (bf16_t)v[0]; o[1] = (bf16_t)v[1]; o[2] = (bf16_t)v[2]; o[3] = (bf16_t)v[3];
  return o;
}

// Pack weights into MFMA A-frag order:
//   chunk[(nt*16 + kk)*64 + lane] = w[nt*16 + (lane&15)][kk*32 + (lane>>4)*8 .. +8]
__global__ void prep_kernel(const float* __restrict__ wih_f, const float* __restrict__ whh_f,
                            const float* __restrict__ wout_f,
                            bf16x8* __restrict__ wihPk, bf16x8* __restrict__ whhPk,
                            bf16x8* __restrict__ wopPk) {
  int c = blockIdx.x * 256 + threadIdx.x;
  int lane = c & 63, l15 = lane & 15, lk = (lane >> 4) & 3;
  if (c < 196608) {
    int cid = (c < 98304) ? c : c - 98304;
    const float* src = (c < 98304) ? wih_f : whh_f;
    bf16x8* dst = (c < 98304) ? wihPk : whhPk;
    int kk = (cid >> 6) & 15;
    int nt = cid >> 10;
    const float* p = src + (size_t)(nt * 16 + l15) * 512 + kk * 32 + lk * 8;
    bf16x8 o;
    #pragma unroll
    for (int i = 0; i < 8; ++i) o[i] = (bf16_t)p[i];
    dst[cid] = o;
  } else if (c < 197632) {
    int cid = c - 196608;          // vocab tile: 16 kk * 64 lane
    int kk = cid >> 6;
    bf16x8 o;
    if (l15 < 10) {
      const float* p = wout_f + (size_t)l15 * 512 + kk * 32 + lk * 8;
      #pragma unroll
      for (int i = 0; i < 8; ++i) o[i] = (bf16_t)p[i];
    } else {
      #pragma unroll
      for (int i = 0; i < 8; ++i) o[i] = (bf16_t)0.0f;
    }
    wopPk[cid] = o;
  }
}

__global__ __launch_bounds__(THREADS, 1) void gru_kernel(
    const float* __restrict__ x, const float* __restrict__ b_ih,
    const float* __restrict__ b_hh, const float* __restrict__ b_out,
    const bf16x8* __restrict__ wih, const bf16x8* __restrict__ whh,
    const bf16x8* __restrict__ wop,
    bf16x4* __restrict__ gi, float* __restrict__ out) {
  // Two h tiles: 64 rows x 512 bf16 (row = 1024B); logical col-byte L of
  // row r stored at physical L ^ ((r&7)<<4). hA/hB alternate per step with
  // COMPILE-TIME bases (alias-disjoint for the scheduler).
  __shared__ __align__(16) char hlds[2 * BUFB];
  char* const hA = hlds;
  char* const hB = hlds + BUFB;

  const int tid   = (int)threadIdx.x;
  const int lane  = tid & 63;
  const int wq    = tid >> 6;      // 0..7: wave owns jtiles [wq*4, wq*4+4)
  const int l15   = lane & 15;
  const int lk    = lane >> 4;
  const int brow0 = (int)blockIdx.x * BM;
  const int swz   = (l15 & 7) << 4;
  const int kbase = (lk * 16) ^ swz;        // b128 read col base (XOR with kk*64)
  const int cbase = (lk * 8) ^ swz;         // b64 cell col base (XOR with jt*32)

  // ---------------- phase 0: x -> bf16 -> hA (h0 = x) ----------------
  #pragma unroll
  for (int it = 0; it < 16; ++it) {
    int f4  = it * THREADS + tid;
    int row = f4 >> 7, c4 = f4 & 127;
    float4 v = ((const float4*)(x + (size_t)(brow0 + row) * 512))[c4];
    bf16x4 h4 = { (bf16_t)v.x, (bf16_t)v.y, (bf16_t)v.z, (bf16_t)v.w };
    *(bf16x4*)(&hA[row * 1024 + ((c4 * 8) ^ ((row & 7) << 4))]) = h4;
  }
  __syncthreads();

  const size_t gibase = (size_t)blockIdx.x * 24576;  // bf16x4 chunks per block
  // gi chunk: (jt*12 + g*4 + bt)*64 + lane,  jt = wq*4 + p

  // ---------------- gi phase: gi = x @ w_ih^T + biases ----------------
  #pragma unroll
  for (int p = 0; p < 4; ++p) {
    const int jt = wq * 4 + p;
    f32x4 acc[3][4];
    #pragma unroll
    for (int g = 0; g < 3; ++g)
      #pragma unroll
      for (int bt = 0; bt < 4; ++bt) acc[g][bt] = (f32x4){0.f, 0.f, 0.f, 0.f};

    #pragma unroll 4
    for (int kk = 0; kk < 16; ++kk) {
      bf16x8 hf[4];
      #pragma unroll
      for (int bt = 0; bt < 4; ++bt)
        hf[bt] = *(const bf16x8*)(&hA[(bt * 16 + l15) * 1024 + ((kk * 64) ^ kbase)]);
      #pragma unroll
      for (int g = 0; g < 3; ++g) {
        bf16x8 wf = wih[((g * 32 + jt) * 16 + kk) * 64 + lane];
        #pragma unroll
        for (int bt = 0; bt < 4; ++bt)
          acc[g][bt] = __builtin_amdgcn_mfma_f32_16x16x32_bf16(wf, hf[bt], acc[g][bt], 0, 0, 0);
      }
    }
    {
      int j = jt * 16 + lk * 4;
      f32x4 b0 = *(const f32x4*)(b_ih + j) + *(const f32x4*)(b_hh + j);
      f32x4 b1 = *(const f32x4*)(b_ih + 512 + j) + *(const f32x4*)(b_hh + 512 + j);
      f32x4 b2 = *(const f32x4*)(b_ih + 1024 + j);   // b_hh_n stays separate (x r)
      #pragma unroll
      for (int bt = 0; bt < 4; ++bt) {
        int cb = jt * 12 + bt;
        gi[gibase + ((size_t)(cb + 0) << 6) + lane] = pk4(acc[0][bt] + b0);
        gi[gibase + ((size_t)(cb + 4) << 6) + lane] = pk4(acc[1][bt] + b1);
        gi[gibase + ((size_t)(cb + 8) << 6) + lane] = pk4(acc[2][bt] + b2);
      }
    }
  }
  // (no barrier: hA unchanged; gi is same-lane RAW, HW-ordered)

  // ---------------- 6 recurrent steps, unrolled x2 (static buffers) -------
  #pragma unroll
  for (int t = 0; t < NSTEP; ++t) {
    // compile-time buffer selection (t-loop fully unrolled)
    char* const rd = (t & 1) ? hB : hA;
    char* const wr = (t & 1) ? hA : hB;

    #pragma unroll
    for (int p = 0; p < 4; ++p) {
      const int jt = wq * 4 + p;
      const int cb = jt * 12;

      // prefetch this pass's gi chunks (latency hides under the k-loop)
      bf16x4 gpre[3][4];
      #pragma unroll
      for (int g = 0; g < 3; ++g)
        #pragma unroll
        for (int bt = 0; bt < 4; ++bt)
          gpre[g][bt] = gi[gibase + ((size_t)(cb + g * 4 + bt) << 6) + lane];

      f32x4 acc[3][4];
      #pragma unroll
      for (int g = 0; g < 3; ++g)
        #pragma unroll
        for (int bt = 0; bt < 4; ++bt) acc[g][bt] = (f32x4){0.f, 0.f, 0.f, 0.f};

      #pragma unroll 4
      for (int kk = 0; kk < 16; ++kk) {
        bf16x8 hf[4];
        #pragma unroll
        for (int bt = 0; bt < 4; ++bt)
          hf[bt] = *(const bf16x8*)(&rd[(bt * 16 + l15) * 1024 + ((kk * 64) ^ kbase)]);
        #pragma unroll
        for (int g = 0; g < 3; ++g) {
          bf16x8 wf = whh[((g * 32 + jt) * 16 + kk) * 64 + lane];
          #pragma unroll
          for (int bt = 0; bt < 4; ++bt)
            acc[g][bt] = __builtin_amdgcn_mfma_f32_16x16x32_bf16(wf, hf[bt], acc[g][bt], 0, 0, 0);
        }
      }
      // GRU cell epilogue: overlaps next pass's k-loop (disjoint static LDS)
      {
        int j = jt * 16 + lk * 4;
        f32x4 bn4 = *(const f32x4*)(b_hh + 1024 + j);
        #pragma unroll
        for (int bt = 0; bt < 4; ++bt) {
          f32x4 gr  = up4(gpre[0][bt]);
          f32x4 gz  = up4(gpre[1][bt]);
          f32x4 gn  = up4(gpre[2][bt]);
          f32x4 hov = up4(*(const bf16x4*)(&rd[(bt * 16 + l15) * 1024 +
                                               ((jt * 32) ^ cbase)]));
          f32x4 hv;
          #pragma unroll
          for (int r = 0; r < 4; ++r) {
            float rv = sigm(gr[r] + acc[0][bt][r]);
            float zv = sigm(gz[r] + acc[1][bt][r]);
            float nv = tanhf_(gn[r] + rv * (acc[2][bt][r] + bn4[r]));
            hv[r] = zv * (hov[r] - nv) + nv;     // = (1-z)*n + z*h
          }
          *(bf16x4*)(&wr[(bt * 16 + l15) * 1024 + ((jt * 32) ^ cbase)]) = pk4(hv);
        }
      }
    }
    __syncthreads();   // h_{t+1} (wr) writes drained & visible; rd reads done

    // logits_t = h_{t+1} @ w_out^T + b_out ; waves 0..3 each own one btile.
    // Concurrent with other waves' next-step k-loop (both only read wr;
    // next step's epilogue writes go to rd — disjoint static bases).
    if (wq < 4) {
      f32x4 lacc = (f32x4){0.f, 0.f, 0.f, 0.f};
      #pragma unroll 4
      for (int kk = 0; kk < 16; ++kk) {
        bf16x8 hf = *(const bf16x8*)(&wr[(wq * 16 + l15) * 1024 + ((kk * 64) ^ kbase)]);
        bf16x8 wf = wop[kk * 64 + lane];
        lacc = __builtin_amdgcn_mfma_f32_16x16x32_bf16(wf, hf, lacc, 0, 0, 0);
      }
      size_t ob = (size_t)(brow0 + wq * 16 + l15) * 60 + t * 10 + lk * 4;
      if (lk < 2) {
        f32x2 a = { lacc[0] + b_out[lk * 4 + 0], lacc[1] + b_out[lk * 4 + 1] };
        f32x2 b = { lacc[2] + b_out[lk * 4 + 2], lacc[3] + b_out[lk * 4 + 3] };
        *(f32x2*)(out + ob) = a;
        *(f32x2*)(out + ob + 2) = b;
      } else if (lk == 2) {
        f32x2 a = { lacc[0] + b_out[8], lacc[1] + b_out[9] };
        *(f32x2*)(out + ob) = a;
      }
    }
  }
}

extern "C" void kernel_launch(void* const* d_in, const int* in_sizes, int n_in,
                              void* d_out, int out_size, void* d_ws, size_t ws_size,
                              hipStream_t stream) {
  const float* x     = (const float*)d_in[0];
  const float* wih_f = (const float*)d_in[1];
  const float* whh_f = (const float*)d_in[2];
  const float* b_ih  = (const float*)d_in[3];
  const float* b_hh  = (const float*)d_in[4];
  const float* wout  = (const float*)d_in[5];
  const float* b_out = (const float*)d_in[6];

  char* ws = (char*)d_ws;
  bf16x8* wihPk = (bf16x8*)(ws + WIH_OFF);
  bf16x8* whhPk = (bf16x8*)(ws + WHH_OFF);
  bf16x8* wopPk = (bf16x8*)(ws + WOP_OFF);
  bf16x4* gi    = (bf16x4*)(ws + GI_OFF);

  prep_kernel<<<772, 256, 0, stream>>>(wih_f, whh_f, wout, wihPk, whhPk, wopPk);
  gru_kernel<<<NBLK, THREADS, 0, stream>>>(x, b_ih, b_hh, b_out,
                                           wihPk, whhPk, wopPk, gi, (float*)d_out);
}